// Round 4
// baseline (56.681 us; speedup 1.0000x reference)
//
#include <hip/hip_runtime.h>
#include <math.h>

// ---------------- problem constants ----------------
namespace {
constexpr int Bc  = 4;
constexpr int Nc  = 8;
constexpr int Lc  = 256;
constexpr int CG  = 128;
constexpr int CHW = 3 * 128 * 128;
constexpr int ROWS = Bc * Lc * Nc;   // 8192 rows per bank
constexpr int SGI  = 2048;           // sampled G rows (stride 4)
constexpr int SPJ  = 4096;           // sampled P rows (stride 2)

// workspace offsets (in floats)
constexpr size_t OFF_GH = 0;                         // 8192*128 ushort = 524288 f
constexpr size_t OFF_PH = OFF_GH + 524288;
constexpr size_t OFF_NG = OFF_PH + 524288;           // 8192 (all G row norms)
constexpr size_t OFF_NP = OFF_NG + 8192;             // 8192
constexpr size_t OFF_P1 = OFF_NP + 8192;             // 512 pdist partials
constexpr size_t OFF_P2 = OFF_P1 + 512;              // 1024 v^2 partials
constexpr size_t OFF_CNT = OFF_P2 + 1024;            // 1 int counter
}  // namespace

typedef __attribute__((ext_vector_type(8))) short bf16x8;
typedef __attribute__((ext_vector_type(4))) float f32x4;

__device__ inline void async16(const void* g, void* lds) {
  __builtin_amdgcn_global_load_lds(
      (const __attribute__((address_space(1))) unsigned int*)g,
      (__attribute__((address_space(3))) unsigned int*)lds, 16, 0, 0);
}
__device__ inline unsigned short f2bf(float x) {
  union { float f; unsigned u; } c; c.f = x;
  unsigned r = c.u + 0x7fffu + ((c.u >> 16) & 1u);  // RNE
  return (unsigned short)(r >> 16);
}
__device__ inline float bf2f(unsigned short u) {
  union { unsigned u32; float f; } c; c.u32 = (unsigned)u << 16; return c.f;
}
__device__ inline float fsqrt(float x) {
  float r; asm("v_sqrt_f32 %0, %1" : "=v"(r) : "v"(x)); return r;
}
__device__ inline float fexp2(float x) {
  float r; asm("v_exp_f32 %0, %1" : "=v"(r) : "v"(x)); return r;
}

// ---------------- K1: conv via bf16 MFMA -> Gh/Ph + row norms ---------------
// grid: 64 images * 8 chunks(32 pos) = 512 blocks, 256 threads (4 waves).
// A = patch diffs [32 pos][192 k] bf16 (XOR-swz), B = W [128 o][192 k] bf16.
// Also zeroes the last-block counter used by k4.
__global__ __launch_bounds__(256) void k1_conv(
    const float* __restrict__ xg, const float* __restrict__ xp,
    const float* __restrict__ xu, const float* __restrict__ W,
    unsigned short* __restrict__ Gh, unsigned short* __restrict__ Ph,
    float* __restrict__ nGf, float* __restrict__ nPf, int* __restrict__ cnt) {
  __shared__ unsigned short Aw[32 * 192];    // 12 KB, row stride 384B
  __shared__ unsigned short Bw[128 * 192];   // 48 KB
  __shared__ float nrmL[32][2];

  const int t = threadIdx.x;
  if (blockIdx.x == 0 && t == 0) *cnt = 0;   // reset ticket for k4
  const int img = blockIdx.x >> 3;
  const int chunk = blockIdx.x & 7;          // 8 chunks of 32 positions
  const int b = img >> 4;
  const int u = img & 15;
  const int n = u & 7;

  const float* src = (u < Nc) ? xg + (size_t)(b * Nc + u) * CHW
                              : xp + (size_t)(b * Nc + n) * CHW;
  const float* up = xu + (size_t)b * CHW;

  // stage W (fp32 -> bf16, swizzled): thread t -> row o=t>>1, 12 octets
  {
    const int o = t >> 1, half = t & 1;
    const int swz = (o & 7) << 4;
    char* bb = (char*)Bw + o * 384;
#pragma unroll
    for (int c = 0; c < 12; ++c) {
      int ci = half * 12 + c;
      float4 w0 = *(const float4*)(W + o * 192 + ci * 8);
      float4 w1 = *(const float4*)(W + o * 192 + ci * 8 + 4);
      union { unsigned short us[8]; bf16x8 v; } pk;
      pk.us[0] = f2bf(w0.x); pk.us[1] = f2bf(w0.y);
      pk.us[2] = f2bf(w0.z); pk.us[3] = f2bf(w0.w);
      pk.us[4] = f2bf(w1.x); pk.us[5] = f2bf(w1.y);
      pk.us[6] = f2bf(w1.z); pk.us[7] = f2bf(w1.w);
      *(bf16x8*)(bb + ((ci * 16) ^ swz)) = pk.v;
    }
  }
  // stage A: 32 pos x 24 octets; 16 consecutive lanes cover lg_lo 0..15
  // of the same octet -> 512B-contiguous global runs.
  {
    const int gq = t >> 4;       // 0..15
    const int lg_lo = t & 15;
#pragma unroll
    for (int i = 0; i < 3; ++i) {
      int combo = gq * 3 + i;    // 0..47
      int oc = combo % 24;
      int lg_hi = combo / 24;    // 0..1
      int lg = lg_hi * 16 + lg_lo;
      int off = ((oc >> 3) * 128 + (chunk * 2 + lg_hi) * 8 + (oc & 7)) * 128 +
                lg_lo * 8;
      float4 s0 = *(const float4*)(src + off);
      float4 s1 = *(const float4*)(src + off + 4);
      float4 u0 = *(const float4*)(up + off);
      float4 u1 = *(const float4*)(up + off + 4);
      union { unsigned short us[8]; bf16x8 v; } pk;
      pk.us[0] = f2bf(s0.x - u0.x); pk.us[1] = f2bf(s0.y - u0.y);
      pk.us[2] = f2bf(s0.z - u0.z); pk.us[3] = f2bf(s0.w - u0.w);
      pk.us[4] = f2bf(s1.x - u1.x); pk.us[5] = f2bf(s1.y - u1.y);
      pk.us[6] = f2bf(s1.z - u1.z); pk.us[7] = f2bf(s1.w - u1.w);
      *(bf16x8*)((char*)Aw + lg * 384 + ((oc * 16) ^ ((lg & 7) << 4))) = pk.v;
    }
  }
  __syncthreads();

  const int lane = t & 63;
  const int w = t >> 6;
  const int wr = w >> 1, wc = w & 1;     // wave: 16 pos x 64 out channels
  const int fr = lane & 15;
  const int kq = lane >> 4;
  const int swz = (fr & 7) << 4;

  f32x4 acc[4] = {};
#pragma unroll
  for (int ks = 0; ks < 6; ++ks) {
    const int kbyte = ks * 64 + kq * 16;
    bf16x8 a = *(const bf16x8*)((const char*)Aw +
               (wr * 16 + fr) * 384 + (kbyte ^ swz));
    bf16x8 bfr[4];
#pragma unroll
    for (int ni = 0; ni < 4; ++ni)
      bfr[ni] = *(const bf16x8*)((const char*)Bw +
                (wc * 64 + ni * 16 + fr) * 384 + (kbyte ^ swz));
#pragma unroll
    for (int ni = 0; ni < 4; ++ni)
      acc[ni] = __builtin_amdgcn_mfma_f32_16x16x32_bf16(a, bfr[ni], acc[ni], 0, 0, 0);
  }

  // store bf16 outputs + per-row squared-norm partials
  unsigned short* dst = (u < Nc) ? Gh : Ph;
  float pr[4];
#pragma unroll
  for (int reg = 0; reg < 4; ++reg) {
    int lg = chunk * 32 + wr * 16 + kq * 4 + reg;   // position in image
    size_t rbase = ((size_t)(b * Lc + lg) * Nc + n) * CG;
    float s = 0.f;
#pragma unroll
    for (int ni = 0; ni < 4; ++ni) {
      float v = acc[ni][reg];
      dst[rbase + wc * 64 + ni * 16 + fr] = f2bf(v);
      s += v * v;
    }
    pr[reg] = s;
  }
#pragma unroll
  for (int m = 1; m <= 8; m <<= 1) {
#pragma unroll
    for (int reg = 0; reg < 4; ++reg) pr[reg] += __shfl_xor(pr[reg], m);
  }
  if (fr == 0) {
#pragma unroll
    for (int reg = 0; reg < 4; ++reg)
      nrmL[wr * 16 + kq * 4 + reg][wc] = pr[reg];
  }
  __syncthreads();
  if (t < 32) {
    int l = chunk * 32 + t;
    float nv = nrmL[t][0] + nrmL[t][1];
    ((u < Nc) ? nGf : nPf)[(size_t)(b * Lc + l) * Nc + n] = nv;
  }
}

// ---------------- K2: sum pdist over 2048(G/4) x 4096(P/2) via MFMA ---------
// grid 512 = 16 i-tiles x 32 j-tiles, XCD-swizzled.
__global__ __launch_bounds__(256) void k2_pdist_mfma(
    const unsigned short* __restrict__ Gh, const unsigned short* __restrict__ Ph,
    const float* __restrict__ nGf, const float* __restrict__ nPf,
    float* __restrict__ part1) {
  __shared__ unsigned short As[128 * 128];  // 32 KB swizzled
  __shared__ unsigned short Bs[128 * 128];

  const int t = threadIdx.x;
  const int lane = t & 63;
  const int w = t >> 6;
  const int bid = blockIdx.x;
  const int nid = (bid & 7) * 64 + (bid >> 3);  // XCD-contiguous strips
  const int it = nid & 15, jt = nid >> 4;
  const int i0s = it * 128;        // sampled G index (global row = 4*idx)
  const int j0s = jt * 128;        // sampled P index (global row = 2*idx)

  const int lsub = lane >> 4;
  const int c16 = (lane & 15) * 16;
#pragma unroll
  for (int q = 0; q < 8; ++q) {
    int rbase = w * 32 + q * 4;
    int lr = rbase + lsub;
    int col2 = c16 ^ ((lr & 7) << 4);
    async16(Gh + (size_t)((i0s + lr) * 4) * CG + (col2 >> 1), &As[rbase * CG]);
    async16(Ph + (size_t)((j0s + lr) * 2) * CG + (col2 >> 1), &Bs[rbase * CG]);
  }
  __syncthreads();

  const int wr = w >> 1, wc = w & 1;
  const int fr = lane & 15;
  const int kq = lane >> 4;
  const int swz = (fr & 7) << 4;

  f32x4 acc[4][4] = {};
#pragma unroll
  for (int kk = 0; kk < 128; kk += 32) {
    int kb = kk * 2 + kq * 16;
    bf16x8 a[4], bfr[4];
#pragma unroll
    for (int mi = 0; mi < 4; ++mi) {
      a[mi] = *(const bf16x8*)((const char*)As +
               (wr * 64 + mi * 16 + fr) * 256 + (kb ^ swz));
      bfr[mi] = *(const bf16x8*)((const char*)Bs +
                (wc * 64 + mi * 16 + fr) * 256 + (kb ^ swz));
    }
#pragma unroll
    for (int mi = 0; mi < 4; ++mi)
#pragma unroll
      for (int ni = 0; ni < 4; ++ni)
        acc[mi][ni] = __builtin_amdgcn_mfma_f32_16x16x32_bf16(
            a[mi], bfr[ni], acc[mi][ni], 0, 0, 0);
  }

  float na[4][4], nb[4];
#pragma unroll
  for (int mi = 0; mi < 4; ++mi)
#pragma unroll
    for (int r = 0; r < 4; ++r)
      na[mi][r] = nGf[(size_t)(i0s + wr * 64 + mi * 16 + kq * 4 + r) * 4];
#pragma unroll
  for (int ni = 0; ni < 4; ++ni)
    nb[ni] = nPf[(size_t)(j0s + wc * 64 + ni * 16 + fr) * 2];

  float ls = 0.f;
#pragma unroll
  for (int mi = 0; mi < 4; ++mi)
#pragma unroll
    for (int ni = 0; ni < 4; ++ni) {
      f32x4 s = acc[mi][ni];
#pragma unroll
      for (int r = 0; r < 4; ++r) {
        float d2 = fmaf(-2.f, s[r], na[mi][r] + nb[ni]);
        ls += fsqrt(fmaxf(d2, 1e-12f));
      }
    }
#pragma unroll
  for (int off = 32; off >= 1; off >>= 1) ls += __shfl_down(ls, off);
  __syncthreads();
  if (lane == 0) ((float*)As)[w] = ls;
  __syncthreads();
  if (t == 0)
    part1[bid] = ((float*)As)[0] + ((float*)As)[1] +
                 ((float*)As)[2] + ((float*)As)[3];
}

// ---------------- K4: per-(b,l) drift + fused final reduce ------------------
__global__ __launch_bounds__(256) void k4_drift(
    const unsigned short* __restrict__ Gh, const unsigned short* __restrict__ Ph,
    const float* __restrict__ p1, const int* __restrict__ epochp,
    float* __restrict__ part2, int* __restrict__ cnt, float* __restrict__ out) {
  __shared__ float xL[8][136], yL[8][136];
  __shared__ float dxy[8][9], dxx[8][9];
  __shared__ float wp[8][9], wsm[8][9];
  __shared__ float redf[4];
  __shared__ double redd[4];
  __shared__ int lastFlag;

  const int t = threadIdx.x;
  const int lane = t & 63;
  const int wv = t >> 6;
  const int bid = blockIdx.x;

  // inline feat_scale from pdist partials (identical in every block)
  float s0 = 0.f;
#pragma unroll
  for (int i = 0; i < 2; ++i) s0 += p1[t + i * 256];
#pragma unroll
  for (int off = 32; off >= 1; off >>= 1) s0 += __shfl_down(s0, off);
  if (lane == 0) redf[wv] = s0;
  __syncthreads();
  float fsv = (redf[0] + redf[1] + redf[2] + redf[3]) *
              (1.0f / 8388608.0f) * 0.08838834764831845f;  // /(2048*4096)/sqrt(128)
  fsv = fmaxf(fsv, 1e-4f);
  const float inv = 1.0f / fsv;

  const int e = epochp[0];
  float lam;
  if (e <= 5) lam = 0.0f;
  else if (e <= 15) lam = ((float)(e - 5) / 10.0f) * 0.5f;
  else lam = 0.5f;

  const unsigned short* gB = Gh + (size_t)bid * (Nc * CG);
  const unsigned short* pB = Ph + (size_t)bid * (Nc * CG);
  for (int idx = t; idx < 512; idx += 256) {
    int n = idx >> 6, c = (idx & 63) * 2;
    ushort2 hg = *(const ushort2*)(gB + n * CG + c);
    ushort2 hp = *(const ushort2*)(pB + n * CG + c);
    xL[n][c] = bf2f(hg.x) * inv; xL[n][c + 1] = bf2f(hg.y) * inv;
    yL[n][c] = bf2f(hp.x) * inv; yL[n][c + 1] = bf2f(hp.y) * inv;
  }
  __syncthreads();

  if (t < 64) {
    int n = t >> 3, m = t & 7;
    float d2 = 0.f;
#pragma unroll 4
    for (int c = 0; c < CG; c += 4) {
      float4 a = *(const float4*)&xL[n][c];
      float4 bb = *(const float4*)&yL[m][c];
      float dx = a.x - bb.x, dy = a.y - bb.y, dz = a.z - bb.z, dw = a.w - bb.w;
      d2 += dx * dx + dy * dy + dz * dz + dw * dw;
    }
    dxy[n][m] = fsqrt(fmaxf(d2, 1e-12f));
  } else if (t < 128) {
    int tt = t - 64;
    int n = tt >> 3, m = tt & 7;
    float d2 = 0.f;
#pragma unroll 4
    for (int c = 0; c < CG; c += 4) {
      float4 a = *(const float4*)&xL[n][c];
      float4 bb = *(const float4*)&xL[m][c];
      float dx = a.x - bb.x, dy = a.y - bb.y, dz = a.z - bb.z, dw = a.w - bb.w;
      d2 += dx * dx + dy * dy + dz * dz + dw * dw;
    }
    float d = fsqrt(fmaxf(d2, 1e-12f));
    if (n == m) d += 1e6f;
    dxx[n][m] = d;
  }
  __syncthreads();

  if (t < 16) {
    int n = t & 7;
    const float* drow = (t < 8) ? dxy[n] : dxx[n];
    float* wrow = (t < 8) ? wp[n] : wsm[n];
    float mx = -1e30f;
#pragma unroll
    for (int m = 0; m < 8; ++m) mx = fmaxf(mx, -drow[m] * 10.0f);
    float ex[8];
    float sm = 0.f;
#pragma unroll
    for (int m = 0; m < 8; ++m) {
      ex[m] = fexp2((-drow[m] * 10.0f - mx) * 1.442695041f);
      sm += ex[m];
    }
    float rs = 1.0f / sm;
#pragma unroll
    for (int m = 0; m < 8; ++m) wrow[m] = ex[m] * rs;
  }
  __syncthreads();

  float ls = 0.f;
  for (int idx = t; idx < Nc * CG; idx += 256) {
    int n = idx >> 7, c = idx & 127;
    float xv = xL[n][c];
    float vp = -xv, vs = -xv;
#pragma unroll
    for (int m = 0; m < 8; ++m) {
      vp += wp[n][m] * yL[m][c];
      vs += wsm[n][m] * xL[m][c];
    }
    float v = vp - lam * vs;
    ls += v * v;
  }
#pragma unroll
  for (int off = 32; off >= 1; off >>= 1) ls += __shfl_down(ls, off);
  __syncthreads();
  if (lane == 0) redf[wv] = ls;
  __syncthreads();

  // last-block final reduce (device-scope atomics; k1 zeroed cnt)
  if (t == 0) {
    float bsum = redf[0] + redf[1] + redf[2] + redf[3];
    __hip_atomic_store(&part2[bid], bsum, __ATOMIC_RELEASE,
                       __HIP_MEMORY_SCOPE_AGENT);
    int ticket = __hip_atomic_fetch_add(cnt, 1, __ATOMIC_ACQ_REL,
                                        __HIP_MEMORY_SCOPE_AGENT);
    lastFlag = (ticket == 1023);
  }
  __syncthreads();
  if (lastFlag) {
    double s = 0.0;
    for (int i = t; i < 1024; i += 256)
      s += (double)__hip_atomic_load(&part2[i], __ATOMIC_RELAXED,
                                     __HIP_MEMORY_SCOPE_AGENT);
#pragma unroll
    for (int off = 32; off >= 1; off >>= 1) s += __shfl_down(s, off);
    if (lane == 0) redd[wv] = s;
    __syncthreads();
    if (t == 0) {
      double S = (redd[0] + redd[1] + redd[2] + redd[3]) / 1048576.0;
      double drift = sqrt(S + 1e-6);
      double nf = fmin(fmax(drift, 0.1), 10.0);
      out[0] = (float)(0.01 * S / (nf * nf));
    }
  }
}

// ---------------- launcher ----------------
extern "C" void kernel_launch(void* const* d_in, const int* in_sizes, int n_in,
                              void* d_out, int out_size, void* d_ws, size_t ws_size,
                              hipStream_t stream) {
  const float* xg = (const float*)d_in[0];
  const float* xp = (const float*)d_in[1];
  const float* xu = (const float*)d_in[2];
  const float* W  = (const float*)d_in[3];
  const int* ep   = (const int*)d_in[4];

  float* ws = (float*)d_ws;
  unsigned short* Gh = (unsigned short*)(ws + OFF_GH);
  unsigned short* Ph = (unsigned short*)(ws + OFF_PH);
  float* nGf = ws + OFF_NG;
  float* nPf = ws + OFF_NP;
  float* p1 = ws + OFF_P1;
  float* p2 = ws + OFF_P2;
  int* cnt = (int*)(ws + OFF_CNT);
  float* out = (float*)d_out;

  k1_conv<<<512, 256, 0, stream>>>(xg, xp, xu, W, Gh, Ph, nGf, nPf, cnt);
  k2_pdist_mfma<<<512, 256, 0, stream>>>(Gh, Ph, nGf, nPf, p1);
  k4_drift<<<1024, 256, 0, stream>>>(Gh, Ph, p1, ep, p2, cnt, out);
}